// Round 3
// baseline (316.395 us; speedup 1.0000x reference)
//
#include <hip/hip_runtime.h>

// x: (16, 3, 1024, 1024) fp32. For each (b,c) plane, corner = x[b,c,0,0];
// out = (x != corner) ? 1.0f : 0.0f.
// Memory-bound: 201 MB in + 201 MB out => ~64 us floor at 6.3 TB/s.

constexpr int PLANE = 1024 * 1024;   // elements per (b,c) plane

__global__ void __launch_bounds__(256)
remover_kernel(const float* __restrict__ x, float* __restrict__ out) {
    const int plane = blockIdx.y;                       // 0..47
    const long long base = (long long)plane * PLANE;

    // Wave-uniform corner load: same address across all lanes -> broadcast,
    // L1-cached after first touch per CU.
    const float c = x[base];

    const long long idx = base + ((long long)blockIdx.x * blockDim.x + threadIdx.x) * 4;

    const float4 v = *reinterpret_cast<const float4*>(x + idx);
    float4 o;
    o.x = (v.x != c) ? 1.0f : 0.0f;
    o.y = (v.y != c) ? 1.0f : 0.0f;
    o.z = (v.z != c) ? 1.0f : 0.0f;
    o.w = (v.w != c) ? 1.0f : 0.0f;
    *reinterpret_cast<float4*>(out + idx) = o;
}

extern "C" void kernel_launch(void* const* d_in, const int* in_sizes, int n_in,
                              void* d_out, int out_size, void* d_ws, size_t ws_size,
                              hipStream_t stream) {
    const float* x = (const float*)d_in[0];
    float* out = (float*)d_out;

    // 16*3 = 48 planes; PLANE/4 float4 per plane; 256 threads/block.
    const int blocks_x = PLANE / 4 / 256;   // 1024
    dim3 grid(blocks_x, 48);
    remover_kernel<<<grid, dim3(256), 0, stream>>>(x, out);
}

// Round 4
// 315.475 us; speedup vs baseline: 1.0029x; 1.0029x over previous
//
#include <hip/hip_runtime.h>

// x: (16, 3, 1024, 1024) fp32. For each (b,c) plane, corner = x[b,c,0,0];
// out = (x != corner) ? 1.0f : 0.0f.
// Memory-bound: 201 MB in + 201 MB out => ~64 us floor at 6.3 TB/s.
//
// Grid-stride version: 128 blocks/plane x 48 planes = 6144 blocks,
// 8 float4 per thread (vs 49152 one-float4 blocks previously).
// Nontemporal load/store: pure streaming, no reuse (402 MB > 256 MB L3).

typedef float f32x4 __attribute__((ext_vector_type(4)));

constexpr int PLANE        = 1024 * 1024;   // elements per (b,c) plane
constexpr int V4_PER_PLANE = PLANE / 4;     // 262144 float4
constexpr int BLOCKS_X     = 128;
constexpr int THREADS      = 256;
constexpr int STRIDE       = BLOCKS_X * THREADS;          // 32768 float4
constexpr int ITERS        = V4_PER_PLANE / STRIDE;       // 8

__global__ void __launch_bounds__(256)
remover_kernel(const float* __restrict__ x, float* __restrict__ out) {
    const int plane = blockIdx.y;                         // 0..47
    const size_t base = (size_t)plane * PLANE;

    // Wave-uniform corner load: broadcast, cached. Keep it a normal load.
    const float c = x[base];

    const f32x4* __restrict__ xin = reinterpret_cast<const f32x4*>(x + base);
    f32x4* __restrict__ o         = reinterpret_cast<f32x4*>(out + base);

    int i = blockIdx.x * THREADS + threadIdx.x;
#pragma unroll
    for (int t = 0; t < ITERS; ++t, i += STRIDE) {
        const f32x4 v = __builtin_nontemporal_load(xin + i);
        f32x4 r;
        r.x = (v.x != c) ? 1.0f : 0.0f;
        r.y = (v.y != c) ? 1.0f : 0.0f;
        r.z = (v.z != c) ? 1.0f : 0.0f;
        r.w = (v.w != c) ? 1.0f : 0.0f;
        __builtin_nontemporal_store(r, o + i);
    }
}

extern "C" void kernel_launch(void* const* d_in, const int* in_sizes, int n_in,
                              void* d_out, int out_size, void* d_ws, size_t ws_size,
                              hipStream_t stream) {
    const float* x = (const float*)d_in[0];
    float* out = (float*)d_out;

    dim3 grid(BLOCKS_X, 48);
    remover_kernel<<<grid, dim3(THREADS), 0, stream>>>(x, out);
}